// Round 4
// baseline (10647.974 us; speedup 1.0000x reference)
//
#include <hip/hip_runtime.h>
#include <math.h>
#include <stdint.h>

#define BATCH  8192
#define HIDDEN 512
#define VOCAB  128
#define NSTEP  127   // SEQ_LEN - 1
#define OUTROW (NSTEP * VOCAB)
#define NG     2048  // 4*HIDDEN gate columns

using half8   = __attribute__((ext_vector_type(8))) _Float16;
using half4   = __attribute__((ext_vector_type(4))) _Float16;
using float4v = __attribute__((ext_vector_type(4))) float;

#define GLD16(g, l) __builtin_amdgcn_global_load_lds( \
    (const __attribute__((address_space(1))) void*)(g), \
    (__attribute__((address_space(3))) void*)(l), 16, 0, 0)

__device__ __forceinline__ float fast_rcp(float x) { return __builtin_amdgcn_rcpf(x); }
__device__ __forceinline__ float fast_sig(float x) { return fast_rcp(1.0f + __expf(-x)); }
__device__ __forceinline__ float fast_tanh(float x) { return 1.0f - 2.0f * fast_rcp(1.0f + __expf(2.0f * x)); }

// permuted gate-column index -> original W row (gate*512 + jj)
// n' = bn*128 + wv*64 + gate*16 + jjl  with jj = bn*32 + wv*16 + jjl
__device__ __forceinline__ int orig_row_of(int np) {
    int bn = np >> 7, cc = np & 127;
    int wv = cc >> 6, cw = cc & 63;
    int gate = cw >> 4, jjl = cw & 15;
    int jj = bn * 32 + wv * 16 + jjl;
    return gate * HIDDEN + jj;
}

__global__ __launch_bounds__(256) void init_tok_kernel(int* __restrict__ tok) {
    int i = blockIdx.x * 256 + threadIdx.x;
    if (i < BATCH) tok[i] = 0;
}

__global__ __launch_bounds__(256) void prep_whh_kernel(
    const float* __restrict__ Whh, _Float16* __restrict__ wh, _Float16* __restrict__ wl)
{
    int np = blockIdx.x;
    int orig = orig_row_of(np);
    for (int k = threadIdx.x; k < HIDDEN; k += 256) {
        float w = Whh[(size_t)orig * HIDDEN + k] * 2048.0f;
        _Float16 h = (_Float16)w;
        wh[(size_t)np * HIDDEN + k] = h;
        wl[(size_t)np * HIDDEN + k] = (_Float16)(w - (float)h);
    }
}

__global__ __launch_bounds__(128) void prep_wih_kernel(
    const float* __restrict__ Wih, const float* __restrict__ bih,
    const float* __restrict__ bhh, float* __restrict__ wihT, float* __restrict__ bcomb)
{
    int np = blockIdx.x;
    int orig = orig_row_of(np);
    int v = threadIdx.x;
    wihT[(size_t)v * NG + np] = Wih[(size_t)orig * VOCAB + v];
    if (v == 0) bcomb[np] = bih[orig] + bhh[orig];
}

__global__ __launch_bounds__(256) void prep_wfc_kernel(
    const float* __restrict__ Wfc, _Float16* __restrict__ wh, _Float16* __restrict__ wl)
{
    int i = blockIdx.x * 256 + threadIdx.x;   // 128*512 = 65536 elems
    float w = Wfc[i] * 2048.0f;
    _Float16 h = (_Float16)w;
    wh[i] = h;
    wl[i] = (_Float16)(w - (float)h);
}

__global__ __launch_bounds__(256) void prep_z_kernel(
    const float* __restrict__ z, _Float16* __restrict__ zh, _Float16* __restrict__ zl)
{
    int i = blockIdx.x * 256 + threadIdx.x;
    float4 v = ((const float4*)z)[i];
    float s0 = v.x * 2048.f, s1 = v.y * 2048.f, s2 = v.z * 2048.f, s3 = v.w * 2048.f;
    _Float16 h0 = (_Float16)s0, h1 = (_Float16)s1, h2 = (_Float16)s2, h3 = (_Float16)s3;
    half4 H = {h0, h1, h2, h3};
    half4 L = {(_Float16)(s0 - (float)h0), (_Float16)(s1 - (float)h1),
               (_Float16)(s2 - (float)h2), (_Float16)(s3 - (float)h3)};
    ((half4*)zh)[i] = H;
    ((half4*)zl)[i] = L;
}

// c0 = relu(z @ W_cz^T + b_cz), fp32 (runs once)
__global__ __launch_bounds__(256) void c0_kernel(
    const float* __restrict__ z, const float* __restrict__ Wcz,
    const float* __restrict__ bcz, float* __restrict__ c)
{
    __shared__ float As[16][128];
    __shared__ float Bs[16][128];
    const int m0 = blockIdx.x * 128;
    const int n0 = blockIdx.y * 128;
    const int tid = threadIdx.x;
    const int ty = tid >> 4, tx = tid & 15;

    float acc[8][8];
#pragma unroll
    for (int i = 0; i < 8; ++i)
#pragma unroll
        for (int j = 0; j < 8; ++j) acc[i][j] = 0.f;

    for (int kc = 0; kc < HIDDEN; kc += 16) {
#pragma unroll
        for (int i = 0; i < 2; ++i) {
            int id = tid * 2 + i;
            int row = id >> 2;
            int kq = (id & 3) * 4;
            float4 av = *(const float4*)(z + (size_t)(m0 + row) * HIDDEN + kc + kq);
            As[kq + 0][row] = av.x; As[kq + 1][row] = av.y;
            As[kq + 2][row] = av.z; As[kq + 3][row] = av.w;
            float4 bv = *(const float4*)(Wcz + (size_t)(n0 + row) * HIDDEN + kc + kq);
            Bs[kq + 0][row] = bv.x; Bs[kq + 1][row] = bv.y;
            Bs[kq + 2][row] = bv.z; Bs[kq + 3][row] = bv.w;
        }
        __syncthreads();
#pragma unroll 4
        for (int k = 0; k < 16; ++k) {
            float a[8], b[8];
            *(float4*)&a[0] = *(const float4*)&As[k][ty * 8];
            *(float4*)&a[4] = *(const float4*)&As[k][ty * 8 + 4];
            *(float4*)&b[0] = *(const float4*)&Bs[k][tx * 8];
            *(float4*)&b[4] = *(const float4*)&Bs[k][tx * 8 + 4];
#pragma unroll
            for (int i = 0; i < 8; ++i)
#pragma unroll
                for (int j = 0; j < 8; ++j)
                    acc[i][j] = fmaf(a[i], b[j], acc[i][j]);
        }
        __syncthreads();
    }
#pragma unroll
    for (int i = 0; i < 8; ++i) {
        int m = m0 + ty * 8 + i;
#pragma unroll
        for (int j = 0; j < 8; ++j) {
            int n = n0 + tx * 8 + j;
            c[(size_t)m * HIDDEN + n] = fmaxf(acc[i][j] + bcz[n], 0.f);
        }
    }
}

// Fused LSTM step, fp16x3 split MFMA (ah*bh + ah*bl + al*bh), counted-vmcnt pipeline.
// Block 256(M) x 256(N'), 512 threads = 8 waves (2M x 4N), wave tile 128x64.
// Grid 32x8 = 256 blocks = 1 per CU (LDS 128 KB).
__global__ __launch_bounds__(512, 2) void lstm_mfma_kernel(
    const _Float16* __restrict__ hin_h, const _Float16* __restrict__ hin_l,
    const _Float16* __restrict__ whh_h, const _Float16* __restrict__ whh_l,
    const float* __restrict__ wihT, const float* __restrict__ bcomb,
    const int* __restrict__ tok, float* __restrict__ c,
    _Float16* __restrict__ hout_h, _Float16* __restrict__ hout_l)
{
    __shared__ _Float16 Ah_s[2][256][32];   // 32 KB
    __shared__ _Float16 Al_s[2][256][32];   // 32 KB
    __shared__ _Float16 Bh_s[2][256][32];   // 32 KB
    __shared__ _Float16 Bl_s[2][256][32];   // 32 KB

    const int tid  = threadIdx.x;
    const int wid  = tid >> 6, lane = tid & 63;
    const int wr   = wid >> 2, wc = wid & 3;
    const int m0   = blockIdx.x * 256;
    const int n0   = blockIdx.y * 256;

    float4v acc[8][4];
#pragma unroll
    for (int i = 0; i < 8; ++i)
#pragma unroll
        for (int j = 0; j < 4; ++j) acc[i][j] = (float4v){0.f, 0.f, 0.f, 0.f};

    // staging: each wave stages 32 rows of each of the 4 planes (8 GLD16 total).
    const int lrow = lane >> 2;
    const int lchk = (lane & 3) ^ ((lane >> 3) & 3);
    const int loff = lrow * HIDDEN + lchk * 8;
    const int base = wid * 32;

    const _Float16* agh = hin_h + (size_t)(m0 + base) * HIDDEN + loff;
    const _Float16* agl = hin_l + (size_t)(m0 + base) * HIDDEN + loff;
    const _Float16* bgh = whh_h + (size_t)(n0 + base) * HIDDEN + loff;
    const _Float16* bgl = whh_l + (size_t)(n0 + base) * HIDDEN + loff;

    auto STAGE = [&](int buf, int kc) {
        GLD16(agh + kc,               &Ah_s[buf][base][0]);
        GLD16(agh + kc + 16 * HIDDEN, &Ah_s[buf][base + 16][0]);
        GLD16(agl + kc,               &Al_s[buf][base][0]);
        GLD16(agl + kc + 16 * HIDDEN, &Al_s[buf][base + 16][0]);
        GLD16(bgh + kc,               &Bh_s[buf][base][0]);
        GLD16(bgh + kc + 16 * HIDDEN, &Bh_s[buf][base + 16][0]);
        GLD16(bgl + kc,               &Bl_s[buf][base][0]);
        GLD16(bgl + kc + 16 * HIDDEN, &Bl_s[buf][base + 16][0]);
    };

    // fragment read: row = tile16*16 + t, K-chunk q = lane>>4, swizzled offset
    const int t = lane & 15, qr = lane >> 4;
    const int qa = (qr ^ ((t >> 1) & 3)) * 8;

    STAGE(0, 0);
    for (int k = 0; k < 16; ++k) {
        const int cur = k & 1;
        if (k < 15) STAGE(cur ^ 1, (k + 1) * 32);
        if (k < 15) { asm volatile("s_waitcnt vmcnt(8)" ::: "memory"); }
        else        { asm volatile("s_waitcnt vmcnt(0)" ::: "memory"); }
        __builtin_amdgcn_s_barrier();
        __builtin_amdgcn_sched_barrier(0);

        {
            const _Float16 (*AhC)[32] = Ah_s[cur];
            const _Float16 (*AlC)[32] = Al_s[cur];
            const _Float16 (*BhC)[32] = Bh_s[cur];
            const _Float16 (*BlC)[32] = Bl_s[cur];
            half8 bh[4], bl[4];
#pragma unroll
            for (int j = 0; j < 4; ++j) {
                bh[j] = *(const half8*)&BhC[wc * 64 + j * 16 + t][qa];
                bl[j] = *(const half8*)&BlC[wc * 64 + j * 16 + t][qa];
            }
#pragma unroll
            for (int i = 0; i < 8; ++i) {
                half8 ah = *(const half8*)&AhC[wr * 128 + i * 16 + t][qa];
                half8 al = *(const half8*)&AlC[wr * 128 + i * 16 + t][qa];
#pragma unroll
                for (int j = 0; j < 4; ++j) {
                    acc[i][j] = __builtin_amdgcn_mfma_f32_16x16x32_f16(ah, bh[j], acc[i][j], 0, 0, 0);
                    acc[i][j] = __builtin_amdgcn_mfma_f32_16x16x32_f16(ah, bl[j], acc[i][j], 0, 0, 0);
                    acc[i][j] = __builtin_amdgcn_mfma_f32_16x16x32_f16(al, bh[j], acc[i][j], 0, 0, 0);
                }
            }
        }
        __builtin_amdgcn_sched_barrier(0);
        if (k < 15) {
            asm volatile("" ::: "memory");
            __builtin_amdgcn_s_barrier();   // WAR guard before next STAGE
        }
    }

    // epilogue: wave column wc covers gate group g; lane t owns jj, 4 gates in acc[.][0..3]
    const float INV22 = 1.0f / 4194304.0f;   // 2^-22
    const int g  = blockIdx.y * 4 + wc;
    const int jj = (g >> 1) * 32 + (g & 1) * 16 + t;
    const int colb = n0 + wc * 64 + t;
    float bias[4];
    int   col[4];
#pragma unroll
    for (int j = 0; j < 4; ++j) {
        col[j]  = colb + j * 16;
        bias[j] = bcomb[col[j]];
    }
#pragma unroll
    for (int i = 0; i < 8; ++i) {
        int mb = m0 + wr * 128 + i * 16 + qr * 4;
#pragma unroll
        for (int r = 0; r < 4; ++r) {
            int m  = mb + r;
            int tk = tok[m];
            const float* wv = wihT + (size_t)tk * NG;
            float iv = acc[i][0][r] * INV22 + bias[0] + wv[col[0]];
            float fv = acc[i][1][r] * INV22 + bias[1] + wv[col[1]];
            float gv = acc[i][2][r] * INV22 + bias[2] + wv[col[2]];
            float ov = acc[i][3][r] * INV22 + bias[3] + wv[col[3]];
            float ig = fast_sig(iv);
            float fg = fast_sig(fv);
            float gg = fast_tanh(gv);
            float og = fast_sig(ov);
            size_t ci = (size_t)m * HIDDEN + jj;
            float cn = fg * c[ci] + ig * gg;
            c[ci] = cn;
            float hn = og * fast_tanh(cn);
            float hs = hn * 2048.f;
            _Float16 hh = (_Float16)hs;
            hout_h[ci] = hh;
            hout_l[ci] = (_Float16)(hs - (float)hh);
        }
    }
}

// logits = relu(h @ W_fc^T + b_fc) via fp16x3 MFMA; write out[:,t,:]; tok = argmax.
// Block 32(M) x 128(N), 128 threads = 2 waves, each wave 16 rows. BK=64, swizzled.
// NOTE: pure function of (h, weights) -> (out_t, tok); idempotent.
__global__ __launch_bounds__(128) void logits_mfma_kernel(
    const _Float16* __restrict__ hh_, const _Float16* __restrict__ hl_,
    const _Float16* __restrict__ wfc_h, const _Float16* __restrict__ wfc_l,
    const float* __restrict__ b_fc, float* __restrict__ out_t, int* __restrict__ tok)
{
    __shared__ _Float16 Ah[32][64];
    __shared__ _Float16 Al[32][64];
    __shared__ _Float16 Bh[128][64];
    __shared__ _Float16 Bl[128][64];

    const int tid = threadIdx.x;
    const int wid = tid >> 6, lane = tid & 63;
    const int m0  = blockIdx.x * 32;
    const int t   = lane & 15, qr = lane >> 4;

    float4v acc[8];
#pragma unroll
    for (int j = 0; j < 8; ++j) acc[j] = (float4v){0.f, 0.f, 0.f, 0.f};

    // staging: 8 rows per GLD16 (row = lane>>3, chunk-slot lane&7, swizzled source)
    const int lrow = lane >> 3;
    const int lchk = (lane & 7) ^ lrow;
    const int loff = lrow * HIDDEN + lchk * 8;

    // wave0 stages Ah + B rows [0,64); wave1 stages Al + B rows [64,128)
    const _Float16* Ag = (wid == 0 ? hh_ : hl_) + (size_t)m0 * HIDDEN + loff;
    _Float16* Adst = (wid == 0) ? &Ah[0][0] : &Al[0][0];
    const _Float16* Bgh = wfc_h + (size_t)(wid * 64) * HIDDEN + loff;
    const _Float16* Bgl = wfc_l + (size_t)(wid * 64) * HIDDEN + loff;

    const int sa = t & 7;   // fragment swizzle key (row & 7 = t & 7)

    for (int kc = 0; kc < HIDDEN; kc += 64) {
#pragma unroll
        for (int s = 0; s < 4; ++s)
            GLD16(Ag + kc + s * 8 * HIDDEN, Adst + (s * 8) * 64);
#pragma unroll
        for (int s = 0; s < 8; ++s) {
            GLD16(Bgh + kc + s * 8 * HIDDEN, &Bh[wid * 64 + s * 8][0]);
            GLD16(Bgl + kc + s * 8 * HIDDEN, &Bl[wid * 64 + s * 8][0]);
        }
        __syncthreads();
#pragma unroll
        for (int kh = 0; kh < 2; ++kh) {
            int q = kh * 4 + qr;
            int arow = wid * 16 + t;
            half8 a_h = *(const half8*)&Ah[arow][(q ^ sa) * 8];
            half8 a_l = *(const half8*)&Al[arow][(q ^ sa) * 8];
#pragma unroll
            for (int j = 0; j < 8; ++j) {
                half8 b_h = *(const half8*)&Bh[j * 16 + t][(q ^ sa) * 8];
                half8 b_l = *(const half8*)&Bl[j * 16 + t][(q ^ sa) * 8];
                acc[j] = __builtin_amdgcn_mfma_f32_16x16x32_f16(a_h, b_h, acc[j], 0, 0, 0);
                acc[j] = __builtin_amdgcn_mfma_f32_16x16x32_f16(a_h, b_l, acc[j], 0, 0, 0);
                acc[j] = __builtin_amdgcn_mfma_f32_16x16x32_f16(a_l, b_h, acc[j], 0, 0, 0);
            }
        }
        __syncthreads();
    }

    const float INV22 = 1.0f / 4194304.0f;
    float bv[8];
#pragma unroll
    for (int j = 0; j < 8; ++j) bv[j] = b_fc[j * 16 + t];

#pragma unroll
    for (int r = 0; r < 4; ++r) {
        int m = m0 + wid * 16 + qr * 4 + r;
        float vals[8];
        float vbest = -1.0f; int ibest = 0;
#pragma unroll
        for (int j = 0; j < 8; ++j) {
            float x = fmaxf(acc[j][r] * INV22 + bv[j], 0.f);
            vals[j] = x;
            if (x > vbest) { vbest = x; ibest = j * 16 + t; }
        }
        float* op = out_t + (size_t)m * OUTROW;
#pragma unroll
        for (int j = 0; j < 8; ++j) op[j * 16 + t] = vals[j];
        // argmax across the 16 lanes of this quad (first-max tie semantics)
#pragma unroll
        for (int d = 1; d < 16; d <<= 1) {
            float vo = __shfl_xor(vbest, d, 64);
            int   io = __shfl_xor(ibest, d, 64);
            if (vo > vbest || (vo == vbest && io < ibest)) { vbest = vo; ibest = io; }
        }
        if (t == 0) tok[m] = ibest;
    }
}

extern "C" void kernel_launch(void* const* d_in, const int* in_sizes, int n_in,
                              void* d_out, int out_size, void* d_ws, size_t ws_size,
                              hipStream_t stream)
{
    const float* z    = (const float*)d_in[0];
    const float* W_ih = (const float*)d_in[1];
    const float* W_hh = (const float*)d_in[2];
    const float* b_ih = (const float*)d_in[3];
    const float* b_hh = (const float*)d_in[4];
    const float* W_cz = (const float*)d_in[5];
    const float* b_cz = (const float*)d_in[6];
    const float* W_fc = (const float*)d_in[7];
    const float* b_fc = (const float*)d_in[8];
    float* out = (float*)d_out;

    uint8_t* p = (uint8_t*)d_ws;
    float* c = (float*)p;            p += (size_t)BATCH * HIDDEN * 4;   // 16 MB
    _Float16* sA_h = (_Float16*)p;   p += (size_t)BATCH * HIDDEN * 2;   // 8 MB each
    _Float16* sA_l = (_Float16*)p;   p += (size_t)BATCH * HIDDEN * 2;
    _Float16* sB_h = (_Float16*)p;   p += (size_t)BATCH * HIDDEN * 2;
    _Float16* sB_l = (_Float16*)p;   p += (size_t)BATCH * HIDDEN * 2;
    _Float16* whhh = (_Float16*)p;   p += (size_t)NG * HIDDEN * 2;      // 2 MB each
    _Float16* whhl = (_Float16*)p;   p += (size_t)NG * HIDDEN * 2;
    _Float16* wfch = (_Float16*)p;   p += (size_t)VOCAB * HIDDEN * 2;   // 128 KB each
    _Float16* wfcl = (_Float16*)p;   p += (size_t)VOCAB * HIDDEN * 2;
    float* wihT  = (float*)p;        p += (size_t)VOCAB * NG * 4;       // 1 MB
    float* bcomb = (float*)p;        p += (size_t)NG * 4;
    int* tokp    = (int*)p;          p += (size_t)BATCH * 4;

    init_tok_kernel<<<BATCH / 256, 256, 0, stream>>>(tokp);
    prep_whh_kernel<<<NG, 256, 0, stream>>>(W_hh, whhh, whhl);
    prep_wih_kernel<<<NG, 128, 0, stream>>>(W_ih, b_ih, b_hh, wihT, bcomb);
    prep_wfc_kernel<<<(VOCAB * HIDDEN) / 256, 256, 0, stream>>>(W_fc, wfch, wfcl);
    prep_z_kernel<<<(BATCH * HIDDEN / 4) / 256, 256, 0, stream>>>(z, sA_h, sA_l);
    c0_kernel<<<dim3(BATCH / 128, HIDDEN / 128), 256, 0, stream>>>(z, W_cz, b_cz, c);

    for (int t = 0; t < NSTEP; ++t) {
        const _Float16* inh = (t & 1) ? sB_h : sA_h;
        const _Float16* inl = (t & 1) ? sB_l : sA_l;
        _Float16* outh = (t & 1) ? sA_h : sB_h;
        _Float16* outl = (t & 1) ? sA_l : sB_l;
        lstm_mfma_kernel<<<dim3(BATCH / 256, NG / 256), 512, 0, stream>>>(
            inh, inl, whhh, whhl, wihT, bcomb, tokp, c, outh, outl);
        // DIAGNOSTIC (round 4): logits is a pure function -> launch it twice.
        // (dur_us - 8833) / 127 = marginal per-step cost of one logits dispatch.
        // Outputs are bit-identical (second run recomputes the same out/tok).
        logits_mfma_kernel<<<BATCH / 32, 128, 0, stream>>>(
            outh, outl, wfch, wfcl, b_fc, out + (size_t)t * VOCAB, tokp);
        logits_mfma_kernel<<<BATCH / 32, 128, 0, stream>>>(
            outh, outl, wfch, wfcl, b_fc, out + (size_t)t * VOCAB, tokp);
    }
}

// Round 5
// 8630.338 us; speedup vs baseline: 1.2338x; 1.2338x over previous
//
#include <hip/hip_runtime.h>
#include <math.h>
#include <stdint.h>

#define BATCH  8192
#define HIDDEN 512
#define VOCAB  128
#define NSTEP  127   // SEQ_LEN - 1
#define OUTROW (NSTEP * VOCAB)
#define NG     2048  // 4*HIDDEN gate columns

using half8   = __attribute__((ext_vector_type(8))) _Float16;
using half4   = __attribute__((ext_vector_type(4))) _Float16;
using float4v = __attribute__((ext_vector_type(4))) float;

#define GLD16(g, l) __builtin_amdgcn_global_load_lds( \
    (const __attribute__((address_space(1))) void*)(g), \
    (__attribute__((address_space(3))) void*)(l), 16, 0, 0)

__device__ __forceinline__ float fast_rcp(float x) { return __builtin_amdgcn_rcpf(x); }
__device__ __forceinline__ float fast_sig(float x) { return fast_rcp(1.0f + __expf(-x)); }
__device__ __forceinline__ float fast_tanh(float x) { return 1.0f - 2.0f * fast_rcp(1.0f + __expf(2.0f * x)); }

// permuted gate-column index -> original W row (gate*512 + jj)
// n' = bn*128 + wv*64 + gate*16 + jjl  with jj = bn*32 + wv*16 + jjl
__device__ __forceinline__ int orig_row_of(int np) {
    int bn = np >> 7, cc = np & 127;
    int wv = cc >> 6, cw = cc & 63;
    int gate = cw >> 4, jjl = cw & 15;
    int jj = bn * 32 + wv * 16 + jjl;
    return gate * HIDDEN + jj;
}

__global__ __launch_bounds__(256) void init_tok_kernel(int* __restrict__ tok) {
    int i = blockIdx.x * 256 + threadIdx.x;
    if (i < BATCH) tok[i] = 0;
}

__global__ __launch_bounds__(256) void prep_whh_kernel(
    const float* __restrict__ Whh, _Float16* __restrict__ wh, _Float16* __restrict__ wl)
{
    int np = blockIdx.x;
    int orig = orig_row_of(np);
    for (int k = threadIdx.x; k < HIDDEN; k += 256) {
        float w = Whh[(size_t)orig * HIDDEN + k] * 2048.0f;
        _Float16 h = (_Float16)w;
        wh[(size_t)np * HIDDEN + k] = h;
        wl[(size_t)np * HIDDEN + k] = (_Float16)(w - (float)h);
    }
}

__global__ __launch_bounds__(128) void prep_wih_kernel(
    const float* __restrict__ Wih, const float* __restrict__ bih,
    const float* __restrict__ bhh, float* __restrict__ wihT, float* __restrict__ bcomb)
{
    int np = blockIdx.x;
    int orig = orig_row_of(np);
    int v = threadIdx.x;
    wihT[(size_t)v * NG + np] = Wih[(size_t)orig * VOCAB + v];
    if (v == 0) bcomb[np] = bih[orig] + bhh[orig];
}

__global__ __launch_bounds__(256) void prep_wfc_kernel(
    const float* __restrict__ Wfc, _Float16* __restrict__ wh, _Float16* __restrict__ wl)
{
    int i = blockIdx.x * 256 + threadIdx.x;   // 128*512 = 65536 elems
    float w = Wfc[i] * 2048.0f;
    _Float16 h = (_Float16)w;
    wh[i] = h;
    wl[i] = (_Float16)(w - (float)h);
}

__global__ __launch_bounds__(256) void prep_z_kernel(
    const float* __restrict__ z, _Float16* __restrict__ zh, _Float16* __restrict__ zl)
{
    int i = blockIdx.x * 256 + threadIdx.x;
    float4 v = ((const float4*)z)[i];
    float s0 = v.x * 2048.f, s1 = v.y * 2048.f, s2 = v.z * 2048.f, s3 = v.w * 2048.f;
    _Float16 h0 = (_Float16)s0, h1 = (_Float16)s1, h2 = (_Float16)s2, h3 = (_Float16)s3;
    half4 H = {h0, h1, h2, h3};
    half4 L = {(_Float16)(s0 - (float)h0), (_Float16)(s1 - (float)h1),
               (_Float16)(s2 - (float)h2), (_Float16)(s3 - (float)h3)};
    ((half4*)zh)[i] = H;
    ((half4*)zl)[i] = L;
}

// c0 = relu(z @ W_cz^T + b_cz), fp32 (runs once)
__global__ __launch_bounds__(256) void c0_kernel(
    const float* __restrict__ z, const float* __restrict__ Wcz,
    const float* __restrict__ bcz, float* __restrict__ c)
{
    __shared__ float As[16][128];
    __shared__ float Bs[16][128];
    const int m0 = blockIdx.x * 128;
    const int n0 = blockIdx.y * 128;
    const int tid = threadIdx.x;
    const int ty = tid >> 4, tx = tid & 15;

    float acc[8][8];
#pragma unroll
    for (int i = 0; i < 8; ++i)
#pragma unroll
        for (int j = 0; j < 8; ++j) acc[i][j] = 0.f;

    for (int kc = 0; kc < HIDDEN; kc += 16) {
#pragma unroll
        for (int i = 0; i < 2; ++i) {
            int id = tid * 2 + i;
            int row = id >> 2;
            int kq = (id & 3) * 4;
            float4 av = *(const float4*)(z + (size_t)(m0 + row) * HIDDEN + kc + kq);
            As[kq + 0][row] = av.x; As[kq + 1][row] = av.y;
            As[kq + 2][row] = av.z; As[kq + 3][row] = av.w;
            float4 bv = *(const float4*)(Wcz + (size_t)(n0 + row) * HIDDEN + kc + kq);
            Bs[kq + 0][row] = bv.x; Bs[kq + 1][row] = bv.y;
            Bs[kq + 2][row] = bv.z; Bs[kq + 3][row] = bv.w;
        }
        __syncthreads();
#pragma unroll 4
        for (int k = 0; k < 16; ++k) {
            float a[8], b[8];
            *(float4*)&a[0] = *(const float4*)&As[k][ty * 8];
            *(float4*)&a[4] = *(const float4*)&As[k][ty * 8 + 4];
            *(float4*)&b[0] = *(const float4*)&Bs[k][tx * 8];
            *(float4*)&b[4] = *(const float4*)&Bs[k][tx * 8 + 4];
#pragma unroll
            for (int i = 0; i < 8; ++i)
#pragma unroll
                for (int j = 0; j < 8; ++j)
                    acc[i][j] = fmaf(a[i], b[j], acc[i][j]);
        }
        __syncthreads();
    }
#pragma unroll
    for (int i = 0; i < 8; ++i) {
        int m = m0 + ty * 8 + i;
#pragma unroll
        for (int j = 0; j < 8; ++j) {
            int n = n0 + tx * 8 + j;
            c[(size_t)m * HIDDEN + n] = fmaxf(acc[i][j] + bcz[n], 0.f);
        }
    }
}

// Fused LSTM step, fp16x3 split MFMA (ah*bh + ah*bl + al*bh), counted-vmcnt pipeline.
// Block 256(M) x 256(N'), 512 threads = 8 waves (2M x 4N), wave tile 128x64.
// Grid 32x8 = 256 blocks = 1 per CU (LDS 128 KB).
__global__ __launch_bounds__(512, 2) void lstm_mfma_kernel(
    const _Float16* __restrict__ hin_h, const _Float16* __restrict__ hin_l,
    const _Float16* __restrict__ whh_h, const _Float16* __restrict__ whh_l,
    const float* __restrict__ wihT, const float* __restrict__ bcomb,
    const int* __restrict__ tok, float* __restrict__ c,
    _Float16* __restrict__ hout_h, _Float16* __restrict__ hout_l)
{
    __shared__ _Float16 Ah_s[2][256][32];   // 32 KB
    __shared__ _Float16 Al_s[2][256][32];   // 32 KB
    __shared__ _Float16 Bh_s[2][256][32];   // 32 KB
    __shared__ _Float16 Bl_s[2][256][32];   // 32 KB

    const int tid  = threadIdx.x;
    const int wid  = tid >> 6, lane = tid & 63;
    const int wr   = wid >> 2, wc = wid & 3;
    const int m0   = blockIdx.x * 256;
    const int n0   = blockIdx.y * 256;

    float4v acc[8][4];
#pragma unroll
    for (int i = 0; i < 8; ++i)
#pragma unroll
        for (int j = 0; j < 4; ++j) acc[i][j] = (float4v){0.f, 0.f, 0.f, 0.f};

    // staging: each wave stages 32 rows of each of the 4 planes (8 GLD16 total).
    const int lrow = lane >> 2;
    const int lchk = (lane & 3) ^ ((lane >> 3) & 3);
    const int loff = lrow * HIDDEN + lchk * 8;
    const int base = wid * 32;

    const _Float16* agh = hin_h + (size_t)(m0 + base) * HIDDEN + loff;
    const _Float16* agl = hin_l + (size_t)(m0 + base) * HIDDEN + loff;
    const _Float16* bgh = whh_h + (size_t)(n0 + base) * HIDDEN + loff;
    const _Float16* bgl = whh_l + (size_t)(n0 + base) * HIDDEN + loff;

    auto STAGE = [&](int buf, int kc) {
        GLD16(agh + kc,               &Ah_s[buf][base][0]);
        GLD16(agh + kc + 16 * HIDDEN, &Ah_s[buf][base + 16][0]);
        GLD16(agl + kc,               &Al_s[buf][base][0]);
        GLD16(agl + kc + 16 * HIDDEN, &Al_s[buf][base + 16][0]);
        GLD16(bgh + kc,               &Bh_s[buf][base][0]);
        GLD16(bgh + kc + 16 * HIDDEN, &Bh_s[buf][base + 16][0]);
        GLD16(bgl + kc,               &Bl_s[buf][base][0]);
        GLD16(bgl + kc + 16 * HIDDEN, &Bl_s[buf][base + 16][0]);
    };

    // fragment read: row = tile16*16 + t, K-chunk q = lane>>4, swizzled offset
    const int t = lane & 15, qr = lane >> 4;
    const int qa = (qr ^ ((t >> 1) & 3)) * 8;

    STAGE(0, 0);
    for (int k = 0; k < 16; ++k) {
        const int cur = k & 1;
        if (k < 15) STAGE(cur ^ 1, (k + 1) * 32);
        if (k < 15) { asm volatile("s_waitcnt vmcnt(8)" ::: "memory"); }
        else        { asm volatile("s_waitcnt vmcnt(0)" ::: "memory"); }
        __builtin_amdgcn_s_barrier();
        __builtin_amdgcn_sched_barrier(0);

        {
            const _Float16 (*AhC)[32] = Ah_s[cur];
            const _Float16 (*AlC)[32] = Al_s[cur];
            const _Float16 (*BhC)[32] = Bh_s[cur];
            const _Float16 (*BlC)[32] = Bl_s[cur];
            half8 bh[4], bl[4];
#pragma unroll
            for (int j = 0; j < 4; ++j) {
                bh[j] = *(const half8*)&BhC[wc * 64 + j * 16 + t][qa];
                bl[j] = *(const half8*)&BlC[wc * 64 + j * 16 + t][qa];
            }
#pragma unroll
            for (int i = 0; i < 8; ++i) {
                half8 ah = *(const half8*)&AhC[wr * 128 + i * 16 + t][qa];
                half8 al = *(const half8*)&AlC[wr * 128 + i * 16 + t][qa];
#pragma unroll
                for (int j = 0; j < 4; ++j) {
                    acc[i][j] = __builtin_amdgcn_mfma_f32_16x16x32_f16(ah, bh[j], acc[i][j], 0, 0, 0);
                    acc[i][j] = __builtin_amdgcn_mfma_f32_16x16x32_f16(ah, bl[j], acc[i][j], 0, 0, 0);
                    acc[i][j] = __builtin_amdgcn_mfma_f32_16x16x32_f16(al, bh[j], acc[i][j], 0, 0, 0);
                }
            }
        }
        __builtin_amdgcn_sched_barrier(0);
        if (k < 15) {
            asm volatile("" ::: "memory");
            __builtin_amdgcn_s_barrier();   // WAR guard before next STAGE
        }
    }

    // epilogue: wave column wc covers gate group g; lane t owns jj, 4 gates in acc[.][0..3]
    const float INV22 = 1.0f / 4194304.0f;   // 2^-22
    const int g  = blockIdx.y * 4 + wc;
    const int jj = (g >> 1) * 32 + (g & 1) * 16 + t;
    const int colb = n0 + wc * 64 + t;
    float bias[4];
    int   col[4];
#pragma unroll
    for (int j = 0; j < 4; ++j) {
        col[j]  = colb + j * 16;
        bias[j] = bcomb[col[j]];
    }
#pragma unroll
    for (int i = 0; i < 8; ++i) {
        int mb = m0 + wr * 128 + i * 16 + qr * 4;
#pragma unroll
        for (int r = 0; r < 4; ++r) {
            int m  = mb + r;
            int tk = tok[m];
            const float* wv = wihT + (size_t)tk * NG;
            float iv = acc[i][0][r] * INV22 + bias[0] + wv[col[0]];
            float fv = acc[i][1][r] * INV22 + bias[1] + wv[col[1]];
            float gv = acc[i][2][r] * INV22 + bias[2] + wv[col[2]];
            float ov = acc[i][3][r] * INV22 + bias[3] + wv[col[3]];
            float ig = fast_sig(iv);
            float fg = fast_sig(fv);
            float gg = fast_tanh(gv);
            float og = fast_sig(ov);
            size_t ci = (size_t)m * HIDDEN + jj;
            float cn = fg * c[ci] + ig * gg;
            c[ci] = cn;
            float hn = og * fast_tanh(cn);
            float hs = hn * 2048.f;
            _Float16 hh = (_Float16)hs;
            hout_h[ci] = hh;
            hout_l[ci] = (_Float16)(hs - (float)hh);
        }
    }
}

// logits = relu(h @ W_fc^T + b_fc) via fp16x3 MFMA; write out[:,t,:]; tok = argmax.
// RESTRUCTURED (round 5): block 32(M) x 128(N), 256 threads = 4 waves.
// Wave w owns vocab slice [w*32, w*32+32) x all 32 rows; grid 256 = 1 block/CU.
// Triple-buffered LDS (3 x 40 KB), depth-2 prefetch, counted vmcnt (20/10/0).
// Numerics bit-identical to the previous logits kernel (same per-acc K order,
// same fp16x3 term order, same first-max argmax semantics).
__global__ __launch_bounds__(256) void logits_mfma_kernel(
    const _Float16* __restrict__ hh_, const _Float16* __restrict__ hl_,
    const _Float16* __restrict__ wfc_h, const _Float16* __restrict__ wfc_l,
    const float* __restrict__ b_fc, float* __restrict__ out_t, int* __restrict__ tok)
{
    __shared__ _Float16 Ah[3][32][64];    // 12 KB
    __shared__ _Float16 Al[3][32][64];    // 12 KB
    __shared__ _Float16 Bh[3][128][64];   // 48 KB
    __shared__ _Float16 Bl[3][128][64];   // 48 KB
    __shared__ float red_v[32][4];
    __shared__ int   red_i[32][4];

    const int tid = threadIdx.x;
    const int w   = tid >> 6, lane = tid & 63;
    const int m0  = blockIdx.x * 32;
    const int t   = lane & 15, qr = lane >> 4;
    const int sa  = t & 7;   // fragment swizzle key (row & 7 = t & 7)

    float4v acc[2][2];
#pragma unroll
    for (int rt = 0; rt < 2; ++rt)
#pragma unroll
        for (int ct = 0; ct < 2; ++ct) acc[rt][ct] = (float4v){0.f, 0.f, 0.f, 0.f};

    // staging: 8 rows per GLD16 (row = lane>>3, chunk-slot lane&7, swizzled source)
    const int lrow = lane >> 3;
    const int lchk = (lane & 7) ^ lrow;
    const int loff = lrow * HIDDEN + lchk * 8;

    // wave w stages A rows [w*8, w*8+8) (hi+lo) and B rows [w*32, w*32+32) (hi+lo)
    const _Float16* Agh = hh_   + (size_t)(m0 + w * 8) * HIDDEN + loff;
    const _Float16* Agl = hl_   + (size_t)(m0 + w * 8) * HIDDEN + loff;
    const _Float16* Bgh = wfc_h + (size_t)(w * 32) * HIDDEN + loff;
    const _Float16* Bgl = wfc_l + (size_t)(w * 32) * HIDDEN + loff;

    auto STAGE = [&](int buf, int kc) {
        GLD16(Agh + kc, &Ah[buf][w * 8][0]);
        GLD16(Agl + kc, &Al[buf][w * 8][0]);
#pragma unroll
        for (int s = 0; s < 4; ++s) {
            GLD16(Bgh + kc + s * 8 * HIDDEN, &Bh[buf][w * 32 + s * 8][0]);
            GLD16(Bgl + kc + s * 8 * HIDDEN, &Bl[buf][w * 32 + s * 8][0]);
        }
    };

    STAGE(0, 0);
    STAGE(1, 64);
    for (int k = 0; k < 8; ++k) {
        const int cur = k % 3;
        __builtin_amdgcn_s_barrier();              // WAR: all waves done reading slot (k+2)%3
        if (k + 2 < 8) STAGE((k + 2) % 3, (k + 2) * 64);
        if (k <= 5)      { asm volatile("s_waitcnt vmcnt(20)" ::: "memory"); }
        else if (k == 6) { asm volatile("s_waitcnt vmcnt(10)" ::: "memory"); }
        else             { asm volatile("s_waitcnt vmcnt(0)"  ::: "memory"); }
        __builtin_amdgcn_s_barrier();              // all waves' stage(k) landed
        __builtin_amdgcn_sched_barrier(0);

#pragma unroll
        for (int kh = 0; kh < 2; ++kh) {
            const int qo = ((kh * 4 + qr) ^ sa) * 8;
            half8 a_h[2], a_l[2];
#pragma unroll
            for (int rt = 0; rt < 2; ++rt) {
                a_h[rt] = *(const half8*)&Ah[cur][rt * 16 + t][qo];
                a_l[rt] = *(const half8*)&Al[cur][rt * 16 + t][qo];
            }
#pragma unroll
            for (int ct = 0; ct < 2; ++ct) {
                half8 b_h = *(const half8*)&Bh[cur][w * 32 + ct * 16 + t][qo];
                half8 b_l = *(const half8*)&Bl[cur][w * 32 + ct * 16 + t][qo];
#pragma unroll
                for (int rt = 0; rt < 2; ++rt) {
                    acc[rt][ct] = __builtin_amdgcn_mfma_f32_16x16x32_f16(a_h[rt], b_h, acc[rt][ct], 0, 0, 0);
                    acc[rt][ct] = __builtin_amdgcn_mfma_f32_16x16x32_f16(a_h[rt], b_l, acc[rt][ct], 0, 0, 0);
                    acc[rt][ct] = __builtin_amdgcn_mfma_f32_16x16x32_f16(a_l[rt], b_h, acc[rt][ct], 0, 0, 0);
                }
            }
        }
        __builtin_amdgcn_sched_barrier(0);
    }

    const float INV22 = 1.0f / 4194304.0f;
    float bv[2];
    bv[0] = b_fc[w * 32 + t];
    bv[1] = b_fc[w * 32 + 16 + t];

#pragma unroll
    for (int rt = 0; rt < 2; ++rt) {
#pragma unroll
        for (int r = 0; r < 4; ++r) {
            const int rl = rt * 16 + qr * 4 + r;   // local row 0..31
            const int m  = m0 + rl;
            float vbest = -1.0f; int ibest = 0;
            float* op = out_t + (size_t)m * OUTROW + w * 32;
#pragma unroll
            for (int ct = 0; ct < 2; ++ct) {
                float x = fmaxf(acc[rt][ct][r] * INV22 + bv[ct], 0.f);
                op[ct * 16 + t] = x;
                int idx = w * 32 + ct * 16 + t;
                if (x > vbest) { vbest = x; ibest = idx; }
            }
            // argmax across the 16 lanes of this quad (first-max tie semantics)
#pragma unroll
            for (int d = 1; d < 16; d <<= 1) {
                float vo = __shfl_xor(vbest, d, 64);
                int   io = __shfl_xor(ibest, d, 64);
                if (vo > vbest || (vo == vbest && io < ibest)) { vbest = vo; ibest = io; }
            }
            if (t == 0) { red_v[rl][w] = vbest; red_i[rl][w] = ibest; }
        }
    }
    __syncthreads();
    if (tid < 32) {
        float vbest = red_v[tid][0]; int ibest = red_i[tid][0];
#pragma unroll
        for (int ww = 1; ww < 4; ++ww) {
            float v = red_v[tid][ww]; int i2 = red_i[tid][ww];
            if (v > vbest || (v == vbest && i2 < ibest)) { vbest = v; ibest = i2; }
        }
        tok[m0 + tid] = ibest;
    }
}

extern "C" void kernel_launch(void* const* d_in, const int* in_sizes, int n_in,
                              void* d_out, int out_size, void* d_ws, size_t ws_size,
                              hipStream_t stream)
{
    const float* z    = (const float*)d_in[0];
    const float* W_ih = (const float*)d_in[1];
    const float* W_hh = (const float*)d_in[2];
    const float* b_ih = (const float*)d_in[3];
    const float* b_hh = (const float*)d_in[4];
    const float* W_cz = (const float*)d_in[5];
    const float* b_cz = (const float*)d_in[6];
    const float* W_fc = (const float*)d_in[7];
    const float* b_fc = (const float*)d_in[8];
    float* out = (float*)d_out;

    uint8_t* p = (uint8_t*)d_ws;
    float* c = (float*)p;            p += (size_t)BATCH * HIDDEN * 4;   // 16 MB
    _Float16* sA_h = (_Float16*)p;   p += (size_t)BATCH * HIDDEN * 2;   // 8 MB each
    _Float16* sA_l = (_Float16*)p;   p += (size_t)BATCH * HIDDEN * 2;
    _Float16* sB_h = (_Float16*)p;   p += (size_t)BATCH * HIDDEN * 2;
    _Float16* sB_l = (_Float16*)p;   p += (size_t)BATCH * HIDDEN * 2;
    _Float16* whhh = (_Float16*)p;   p += (size_t)NG * HIDDEN * 2;      // 2 MB each
    _Float16* whhl = (_Float16*)p;   p += (size_t)NG * HIDDEN * 2;
    _Float16* wfch = (_Float16*)p;   p += (size_t)VOCAB * HIDDEN * 2;   // 128 KB each
    _Float16* wfcl = (_Float16*)p;   p += (size_t)VOCAB * HIDDEN * 2;
    float* wihT  = (float*)p;        p += (size_t)VOCAB * NG * 4;       // 1 MB
    float* bcomb = (float*)p;        p += (size_t)NG * 4;
    int* tokp    = (int*)p;          p += (size_t)BATCH * 4;

    init_tok_kernel<<<BATCH / 256, 256, 0, stream>>>(tokp);
    prep_whh_kernel<<<NG, 256, 0, stream>>>(W_hh, whhh, whhl);
    prep_wih_kernel<<<NG, 128, 0, stream>>>(W_ih, b_ih, b_hh, wihT, bcomb);
    prep_wfc_kernel<<<(VOCAB * HIDDEN) / 256, 256, 0, stream>>>(W_fc, wfch, wfcl);
    prep_z_kernel<<<(BATCH * HIDDEN / 4) / 256, 256, 0, stream>>>(z, sA_h, sA_l);
    c0_kernel<<<dim3(BATCH / 128, HIDDEN / 128), 256, 0, stream>>>(z, W_cz, b_cz, c);

    for (int t = 0; t < NSTEP; ++t) {
        const _Float16* inh = (t & 1) ? sB_h : sA_h;
        const _Float16* inl = (t & 1) ? sB_l : sA_l;
        _Float16* outh = (t & 1) ? sA_h : sB_h;
        _Float16* outl = (t & 1) ? sA_l : sB_l;
        lstm_mfma_kernel<<<dim3(BATCH / 256, NG / 256), 512, 0, stream>>>(
            inh, inl, whhh, whhl, wihT, bcomb, tokp, c, outh, outl);
        logits_mfma_kernel<<<BATCH / 32, 256, 0, stream>>>(
            outh, outl, wfch, wfcl, b_fc, out + (size_t)t * VOCAB, tokp);
    }
}